// Round 19
// baseline (199.510 us; speedup 1.0000x reference)
//
#include <hip/hip_runtime.h>

#define B_ 2
#define S_ 2048
#define D_ 2048
#define NH 16
#define NKV 8
#define HD 128
#define SCALE 0.08838834764831845f
#define CEXP 0.1275255f          // SCALE * log2(e)
#define RTHR 62.733f             // 8 / CEXP  (defer-max threshold, p <= 2^8)

typedef unsigned short u16;
typedef __attribute__((ext_vector_type(8))) short short8;
typedef __attribute__((ext_vector_type(4))) float f32x4;
typedef __attribute__((ext_vector_type(16))) float f32x16;
typedef __attribute__((ext_vector_type(4))) int i32x4;
typedef __attribute__((ext_vector_type(2))) int i32x2;

#define ASM_VMCNT(N) asm volatile("s_waitcnt vmcnt(" #N ")" ::: "memory")
#define MEMFENCE asm volatile("" ::: "memory")

__device__ __forceinline__ u16 f2b(float f) {
  union { float f; unsigned u; } c; c.f = f;
  unsigned u = c.u;
  return (u16)((u + 0x7fffu + ((u >> 16) & 1u)) >> 16);
}
__device__ __forceinline__ float b2f(u16 h) {
  union { unsigned u; float f; } c; c.u = ((unsigned)h) << 16;
  return c.f;
}
__device__ __forceinline__ float exp2f_fast(float x) {
  float r; asm("v_exp_f32 %0, %1" : "=v"(r) : "v"(x)); return r;
}
__device__ __forceinline__ int cvtpk(float a, float b) {  // low16=bf16(a), high16=bf16(b)
  int r; asm("v_cvt_pk_bf16_f32 %0, %1, %2" : "=v"(r) : "v"(a), "v"(b)); return r;
}
// swap: a.hi32lanes <-> b.lo32lanes (both regs updated)
__device__ __forceinline__ void pl32swap(int& a, int& b) {
  asm volatile("v_permlane32_swap_b32 %0, %1" : "+v"(a), "+v"(b));
}

__device__ __forceinline__ void load_lds16(const u16* g, u16* l) {
  __builtin_amdgcn_global_load_lds(
      (const __attribute__((address_space(1))) unsigned int*)g,
      (__attribute__((address_space(3))) unsigned int*)l, 16, 0, 0);
}

// ---------------- fused f32 -> bf16 conversion (all 5 tensors, 1 launch) ----------------
__global__ __launch_bounds__(256) void cvt_all(const float* __restrict__ x,
                                               const float* __restrict__ wq,
                                               const float* __restrict__ wk,
                                               const float* __restrict__ wv,
                                               const float* __restrict__ wo,
                                               u16* __restrict__ xb,
                                               u16* __restrict__ wqkvb,
                                               u16* __restrict__ wob) {
  const int blk = blockIdx.x;
  const float* src; u16* dst; int base;
  if (blk < 8192)       { src = x;  dst = xb;                  base = blk; }
  else if (blk < 12288) { src = wq; dst = wqkvb;               base = blk - 8192; }
  else if (blk < 14336) { src = wk; dst = wqkvb + 2048 * 2048; base = blk - 12288; }
  else if (blk < 16384) { src = wv; dst = wqkvb + 3072 * 2048; base = blk - 14336; }
  else                  { src = wo; dst = wob;                 base = blk - 16384; }
  int i = base * 256 + threadIdx.x;
  float4 v = ((const float4*)src)[i];
  u16 o0 = f2b(v.x), o1 = f2b(v.y), o2 = f2b(v.z), o3 = f2b(v.w);
  unsigned long long packed = (unsigned long long)o0 | ((unsigned long long)o1 << 16) |
                              ((unsigned long long)o2 << 32) | ((unsigned long long)o3 << 48);
  ((unsigned long long*)dst)[i] = packed;
}

// ---------------- QKV GEMM v2: 128^2 tile, 4 blocks/CU + fused RMSNorm/RoPE/V-T ----------
// gemm_bt3 geometry (measured ~1250 TF on the out-GEMM: single 32KB LDS buffer, 256 thr,
// 4 co-resident blocks/CU cover the vmcnt(0)+barrier stalls). bn tile = one 128-col head:
// bn 0-15 -> Q head bn; 16-23 -> K head bn-16; 24-31 -> V head bn-24. Epilogue identical
// to R16's fused version, with 128-row tok span (wr in {0,1}, sq[2][128]).
__global__ __launch_bounds__(256, 4) void gemm_qkv_fused2(const u16* __restrict__ A,
                                                          const u16* __restrict__ Bm,
                                                          const float* __restrict__ fc,
                                                          const float* __restrict__ qw,
                                                          const float* __restrict__ kw,
                                                          u16* __restrict__ qrope,
                                                          u16* __restrict__ krope,
                                                          u16* __restrict__ vt) {
  __shared__ __align__(16) u16 As[128 * 64];   // 16 KB
  __shared__ __align__(16) u16 Bs[128 * 64];   // 16 KB
  __shared__ float sq[2][128];                 // cross-wave sumsq exchange  1 KB
  const int tid = threadIdx.x;
  const int wave = tid >> 6, lane = tid & 63;
  const int L = (blockIdx.x & 7) * 128 + (blockIdx.x >> 3);  // bijective XCD chunking
  const int bm = L >> 5, bn = L & 31;          // 32 x 32 tile grid
  const int wr = wave >> 1, wc = wave & 1;     // 2M x 2N waves; per-wave 64x64
  const int r = lane & 15, hi = lane >> 4;

  f32x4 acc[4][4];
#pragma unroll
  for (int mi = 0; mi < 4; ++mi)
#pragma unroll
    for (int ni = 0; ni < 4; ++ni) acc[mi][ni] = (f32x4){0.f, 0.f, 0.f, 0.f};

  const int gslot = (lane & 7) ^ (lane >> 3);
  const int srow = lane >> 3;

  auto stage = [&](int k0) {
#pragma unroll
    for (int jj = 0; jj < 4; ++jj) {
      int j = wave * 4 + jj;
      int row = j * 8 + srow;
      load_lds16(A + (size_t)(bm * 128 + row) * 2048 + k0 + gslot * 8, &As[j * 512]);
      load_lds16(Bm + (size_t)(bn * 128 + row) * 2048 + k0 + gslot * 8, &Bs[j * 512]);
    }
  };

  for (int kt = 0; kt < 32; ++kt) {
    stage(kt << 6);
    ASM_VMCNT(0);
    __builtin_amdgcn_s_barrier();
    MEMFENCE;
#pragma unroll
    for (int kc = 0; kc < 2; ++kc) {
      short8 af[4], bfr[4];
#pragma unroll
      for (int m = 0; m < 4; ++m) {
        int row = wr * 64 + m * 16 + r;
        int slot = (hi + kc * 4) ^ (row & 7);
        af[m] = *(const short8*)&As[row * 64 + slot * 8];
      }
#pragma unroll
      for (int n = 0; n < 4; ++n) {
        int row = wc * 64 + n * 16 + r;
        int slot = (hi + kc * 4) ^ (row & 7);
        bfr[n] = *(const short8*)&Bs[row * 64 + slot * 8];
      }
      __builtin_amdgcn_s_setprio(1);
#pragma unroll
      for (int m = 0; m < 4; ++m)
#pragma unroll
        for (int n = 0; n < 4; ++n)
          acc[m][n] = __builtin_amdgcn_mfma_f32_16x16x32_bf16(af[m], bfr[n], acc[m][n], 0, 0, 0);
      __builtin_amdgcn_s_setprio(0);
    }
    MEMFENCE;
    __builtin_amdgcn_s_barrier();   // reads done before next stage overwrites
  }

  // ---- fused epilogue ----
  if (bn >= 24) {
    // V head: store transposed vt[(b*8+hv)*128+d][s]
    const int hv = bn - 24;
#pragma unroll
    for (int mi = 0; mi < 4; ++mi) {
      const int tok0 = bm * 128 + wr * 64 + mi * 16 + hi * 4;
      const int bb = tok0 >> 11, sl = tok0 & 2047;
#pragma unroll
      for (int ni = 0; ni < 4; ++ni) {
        const int d = wc * 64 + ni * 16 + r;
        int w0 = cvtpk(acc[mi][ni][0], acc[mi][ni][1]);
        int w1 = cvtpk(acc[mi][ni][2], acc[mi][ni][3]);
        i32x2 pk = (i32x2){w0, w1};
        *(i32x2*)(vt + ((size_t)(bb * 8 + hv) * 128 + d) * 2048 + sl) = pk;
      }
    }
  } else {
    // Q/K head: RMSNorm over the 128-col row, then RoPE, then store.
    const float* nw = (bn < 16) ? qw : kw;
    float nwv[4];
#pragma unroll
    for (int ni = 0; ni < 4; ++ni) nwv[ni] = nw[wc * 64 + ni * 16 + r];
    float ssq[4][4];
#pragma unroll
    for (int mi = 0; mi < 4; ++mi)
#pragma unroll
      for (int r2 = 0; r2 < 4; ++r2) {
        float s4 = 0.f;
#pragma unroll
        for (int ni = 0; ni < 4; ++ni) {
          float a = acc[mi][ni][r2];
          s4 = __builtin_fmaf(a, a, s4);
        }
#pragma unroll
        for (int mk = 1; mk < 16; mk <<= 1) s4 += __shfl_xor(s4, mk, 64);
        ssq[mi][r2] = s4;
      }
    if (r == 0) {
#pragma unroll
      for (int mi = 0; mi < 4; ++mi)
#pragma unroll
        for (int r2 = 0; r2 < 4; ++r2)
          sq[wc][wr * 64 + mi * 16 + hi * 4 + r2] = ssq[mi][r2];
    }
    __syncthreads();   // block-uniform branch (bn uniform) -> safe
    u16* outp = (bn < 16) ? qrope : krope;
#pragma unroll
    for (int mi = 0; mi < 4; ++mi) {
      const int tok0 = bm * 128 + wr * 64 + mi * 16 + hi * 4;
      const int bb = tok0 >> 11;
      const size_t headbase = (bn < 16) ? ((size_t)(bb * 16 + bn) * 2048)
                                        : ((size_t)(bb * 8 + (bn - 16)) * 2048);
#pragma unroll
      for (int r2 = 0; r2 < 4; ++r2) {
        const int sl = (tok0 + r2) & 2047;
        const float tot = ssq[mi][r2] + sq[wc ^ 1][wr * 64 + mi * 16 + hi * 4 + r2];
        const float rms = rsqrtf(tot * (1.0f / 128.0f) + 1e-6f);
#pragma unroll
        for (int ni = 0; ni < 4; ++ni) {
          const int d = wc * 64 + ni * 16 + r;
          float val = acc[mi][ni][r2] * rms * nwv[ni];
          float prt = __shfl_xor(val, 1, 64);
          const float2 cs = *(const float2*)&fc[(size_t)(sl * 64 + (d >> 1)) * 2];
          float outv = (r & 1) ? (prt * cs.y + val * cs.x)     // odd col: tr*sin + ti*cos
                               : (val * cs.x - prt * cs.y);    // even col: tr*cos - ti*sin
          outp[(headbase + sl) * 128 + d] = f2b(outv);
        }
      }
    }
  }
}

// ---------------- out-GEMM (128^2): single-buffer LDS, co-resident blocks ----------
template<int OUTF32>
__global__ __launch_bounds__(256, 4) void gemm_bt3(const u16* __restrict__ A, const u16* __restrict__ Bm,
                                                   void* __restrict__ Cv, int M, int N, int K, int nbn) {
  __shared__ __align__(16) u16 As[128 * 64];   // 16 KB
  __shared__ __align__(16) u16 Bs[128 * 64];   // 16 KB
  const int tid = threadIdx.x;
  const int wave = tid >> 6, lane = tid & 63;
  const int nwg = gridDim.x, cpx = nwg >> 3;
  const int L = (blockIdx.x & 7) * cpx + (blockIdx.x >> 3);
  const int bm = L / nbn, bn = L % nbn;
  const int wr = wave >> 1, wc = wave & 1;
  const int r = lane & 15, hi = lane >> 4;

  f32x4 acc[4][4];
#pragma unroll
  for (int m = 0; m < 4; ++m)
#pragma unroll
    for (int n = 0; n < 4; ++n) acc[m][n] = (f32x4){0.f, 0.f, 0.f, 0.f};

  const int gslot = (lane & 7) ^ (lane >> 3);
  const int srow = lane >> 3;

  auto stage = [&](int k0) {
#pragma unroll
    for (int jj = 0; jj < 4; ++jj) {
      int j = wave * 4 + jj;
      int row = j * 8 + srow;
      load_lds16(A + (size_t)(bm * 128 + row) * K + k0 + gslot * 8, &As[j * 512]);
      load_lds16(Bm + (size_t)(bn * 128 + row) * K + k0 + gslot * 8, &Bs[j * 512]);
    }
  };

  const int nk = K >> 6;
  for (int kt = 0; kt < nk; ++kt) {
    stage(kt << 6);
    ASM_VMCNT(0);
    __builtin_amdgcn_s_barrier();
    MEMFENCE;
#pragma unroll
    for (int kc = 0; kc < 2; ++kc) {
      short8 af[4], bfr[4];
#pragma unroll
      for (int m = 0; m < 4; ++m) {
        int row = wr * 64 + m * 16 + r;
        int slot = (hi + kc * 4) ^ (row & 7);
        af[m] = *(const short8*)&As[row * 64 + slot * 8];
      }
#pragma unroll
      for (int n = 0; n < 4; ++n) {
        int row = wc * 64 + n * 16 + r;
        int slot = (hi + kc * 4) ^ (row & 7);
        bfr[n] = *(const short8*)&Bs[row * 64 + slot * 8];
      }
#pragma unroll
      for (int m = 0; m < 4; ++m)
#pragma unroll
        for (int n = 0; n < 4; ++n)
          acc[m][n] = __builtin_amdgcn_mfma_f32_16x16x32_bf16(af[m], bfr[n], acc[m][n], 0, 0, 0);
    }
    MEMFENCE;
    __builtin_amdgcn_s_barrier();   // reads done before next stage overwrites
  }

#pragma unroll
  for (int m = 0; m < 4; ++m)
#pragma unroll
    for (int n = 0; n < 4; ++n)
#pragma unroll
      for (int r2 = 0; r2 < 4; ++r2) {
        int grow = bm * 128 + wr * 64 + m * 16 + hi * 4 + r2;
        int gcol = bn * 128 + wc * 64 + n * 16 + r;
        if (OUTF32)
          ((float*)Cv)[(size_t)grow * N + gcol] = acc[m][n][r2];
        else
          ((u16*)Cv)[(size_t)grow * N + gcol] = f2b(acc[m][n][r2]);
      }
}

// ---------------- causal flash attention v9: ONE barrier per step ----------------
__global__ __launch_bounds__(256, 2) void attn9(const u16* __restrict__ qr, const u16* __restrict__ kr,
                                                const u16* __restrict__ vt, u16* __restrict__ ao) {
  __shared__ __align__(16) u16 Ks[2][64 * 128];
  __shared__ __align__(16) u16 Vs[2][128 * 64];
  const int tid = threadIdx.x, wave = tid >> 6, lane = tid & 63;
  const int ql = lane & 31, lh = lane >> 5;

  const int blk = blockIdx.x;
  const int half = blk >> 8;                 // 0: big tiles, 1: complementary small tiles
  const int xcd = blk & 7;
  const int idx = (blk >> 3) & 31;
  const int bh = xcd * 4 + (idx & 3);
  const int pp = idx >> 2;                   // 0..7
  const int t = half ? pp : 15 - pp;
  const int b = bh >> 4, h = bh & 15, hkv = h >> 1;

  const u16* Q  = qr + (size_t)(b * 16 + h) * S_ * HD;
  const u16* Kg = kr + (size_t)(b * 8 + hkv) * S_ * HD;
  const u16* Vg = vt + (size_t)(b * 8 + hkv) * HD * S_;

  const int q0w = t * 128 + wave * 32;
  const int nsteps = 2 * (t + 1);

  short8 qf[8];
#pragma unroll
  for (int ki = 0; ki < 8; ++ki)
    qf[ki] = *(const short8*)(Q + (size_t)(q0w + ql) * HD + ki * 16 + lh * 8);

  f32x16 o[4];
#pragma unroll
  for (int dt = 0; dt < 4; ++dt) o[dt] = 0.f;
  float m = -1e30f, l = 0.f;

  auto stage = [&](int buf, int kv0) {
#pragma unroll
    for (int inst = 0; inst < 4; ++inst) {
      int pp2 = wave * 4096 + inst * 1024 + lane * 16;
      int row = pp2 >> 8;
      int colb = (pp2 & 255) ^ ((row & 7) << 4);
      load_lds16(Kg + (((size_t)(kv0 + row)) << 7) + (colb >> 1),
                 &Ks[buf][(wave * 4096 + inst * 1024) >> 1]);
    }
#pragma unroll
    for (int inst = 0; inst < 4; ++inst) {
      int pp2 = wave * 4096 + inst * 1024 + lane * 16;
      int d = pp2 >> 7;
      int colb = (pp2 & 127) ^ ((d & 7) << 4);
      load_lds16(Vg + (size_t)d * S_ + kv0 + (colb >> 1),
                 &Vs[buf][(wave * 4096 + inst * 1024) >> 1]);
    }
  };

  stage(0, 0);
  for (int i = 0; i < nsteps; ++i) {
    const int kv0 = i * 64;
    const u16* kb = Ks[i & 1];
    const u16* vb = Vs[i & 1];

    ASM_VMCNT(0);                            // my stage(i) loads (issued last iter) done
    __builtin_amdgcn_s_barrier();            // everyone's drained; prev compute reads done
    MEMFENCE;                                // compute reads can't hoist above barrier
    if (i + 1 < nsteps) stage((i + 1) & 1, kv0 + 64);   // prefetch hides under compute(i)

    if (kv0 < q0w + 32) {
      f32x16 sacc[2];
      sacc[0] = 0.f; sacc[1] = 0.f;
      __builtin_amdgcn_s_setprio(1);
#pragma unroll
      for (int ki = 0; ki < 8; ++ki) {
        const int off = ki * 32 + lh * 16;
#pragma unroll
        for (int kvt = 0; kvt < 2; ++kvt) {
          const int row = kvt * 32 + ql;
          short8 kf = *(const short8*)&kb[(row << 7) + ((off ^ ((row & 7) << 4)) >> 1)];
          sacc[kvt] = __builtin_amdgcn_mfma_f32_32x32x16_bf16(kf, qf[ki], sacc[kvt], 0, 0, 0);
        }
      }
      __builtin_amdgcn_s_setprio(0);
      const int q = q0w + ql;
      if (kv0 + 64 > q0w) {
#pragma unroll
        for (int kvt = 0; kvt < 2; ++kvt) {
          const int kvb = kv0 + kvt * 32 + 4 * lh;
#pragma unroll
          for (int reg = 0; reg < 16; ++reg) {
            const int kvr = kvb + (reg & 3) + 8 * (reg >> 2);
            sacc[kvt][reg] = (kvr > q) ? -1e30f : sacc[kvt][reg];
          }
        }
      }
      float mx = sacc[0][0];
#pragma unroll
      for (int kvt = 0; kvt < 2; ++kvt)
#pragma unroll
        for (int reg = 0; reg < 16; ++reg) mx = fmaxf(mx, sacc[kvt][reg]);
      mx = fmaxf(mx, __shfl_xor(mx, 32, 64));
      if (__any(mx > m + RTHR)) {
        float mn = fmaxf(m, mx);
        float sc = exp2f_fast((m - mn) * CEXP);
        l *= sc;
        m = mn;
#pragma unroll
        for (int dt = 0; dt < 4; ++dt)
#pragma unroll
          for (int reg = 0; reg < 16; ++reg) o[dt][reg] *= sc;
      }
      short8 pf[4];
      const float mc = m * CEXP;
      float ps = 0.f;
#pragma unroll
      for (int kvt = 0; kvt < 2; ++kvt) {
        float pv[16];
#pragma unroll
        for (int reg = 0; reg < 16; ++reg) {
          pv[reg] = exp2f_fast(__builtin_fmaf(sacc[kvt][reg], CEXP, -mc));
          ps += pv[reg];
        }
        int A0 = cvtpk(pv[0], pv[1]),  B0 = cvtpk(pv[2], pv[3]);
        int C0 = cvtpk(pv[4], pv[5]),  D0 = cvtpk(pv[6], pv[7]);
        int A1 = cvtpk(pv[8], pv[9]),  B1 = cvtpk(pv[10], pv[11]);
        int C1 = cvtpk(pv[12], pv[13]), D1 = cvtpk(pv[14], pv[15]);
        pl32swap(A0, C0);
        pl32swap(B0, D0);
        pl32swap(A1, C1);
        pl32swap(B1, D1);
        i32x4 w0 = (i32x4){A0, B0, C0, D0};
        i32x4 w1 = (i32x4){A1, B1, C1, D1};
        pf[kvt * 2]     = *(short8*)&w0;
        pf[kvt * 2 + 1] = *(short8*)&w1;
      }
      l += ps;
      __builtin_amdgcn_s_setprio(1);
#pragma unroll
      for (int kc = 0; kc < 4; ++kc) {
        const int off = kc * 32 + lh * 16;
#pragma unroll
        for (int dt = 0; dt < 4; ++dt) {
          const int d = dt * 32 + ql;
          short8 vf = *(const short8*)&vb[(d << 6) + ((off ^ ((d & 7) << 4)) >> 1)];
          o[dt] = __builtin_amdgcn_mfma_f32_32x32x16_bf16(vf, pf[kc], o[dt], 0, 0, 0);
        }
      }
      __builtin_amdgcn_s_setprio(0);
    }
    MEMFENCE;                                // compute reads can't sink below next barrier
  }

  l += __shfl_xor(l, 32, 64);
  const float inv = 1.0f / l;
  const size_t rowoff = ((size_t)(b * 2048 + q0w + ql)) * 2048 + h * 128;
#pragma unroll
  for (int dt = 0; dt < 4; ++dt)
#pragma unroll
    for (int g = 0; g < 4; ++g) {
      const int d0 = dt * 32 + 8 * g + 4 * lh;
      int w0 = cvtpk(o[dt][4 * g] * inv, o[dt][4 * g + 1] * inv);
      int w1 = cvtpk(o[dt][4 * g + 2] * inv, o[dt][4 * g + 3] * inv);
      i32x2 pk = (i32x2){w0, w1};
      *(i32x2*)((u16*)ao + rowoff + d0) = pk;
    }
}

extern "C" void kernel_launch(void* const* d_in, const int* in_sizes, int n_in,
                              void* d_out, int out_size, void* d_ws, size_t ws_size,
                              hipStream_t stream) {
  const float* x = (const float*)d_in[0];
  const float* fc = (const float*)d_in[1];
  const float* wq = (const float*)d_in[2];
  const float* wk = (const float*)d_in[3];
  const float* wv = (const float*)d_in[4];
  const float* wo = (const float*)d_in[5];
  const float* qw = (const float*)d_in[6];
  const float* kw = (const float*)d_in[7];
  float* out = (float*)d_out;
  char* ws = (char*)d_ws;

  u16* xb    = (u16*)(ws);                 // [4096][2048] bf16   16 MB
  u16* wqkvb = (u16*)(ws + 16777216);      // [4096][2048] bf16   16 MB
  u16* wob   = (u16*)(ws + 33554432);      // [2048][2048] bf16    8 MB
  u16* qrope = (u16*)(ws + 75497472);      // [2][16][2048][128]  16 MB
  u16* krope = (u16*)(ws + 92274688);      // [2][8][2048][128]    8 MB
  u16* vtb   = (u16*)(ws + 100663296);     // [2][8][128][2048]    8 MB
  u16* ao    = (u16*)(ws + 109051904);     // [4096][2048] bf16   16 MB

  cvt_all<<<20480, 256, 0, stream>>>(x, wq, wk, wv, wo, xb, wqkvb, wob);

  gemm_qkv_fused2<<<1024, 256, 0, stream>>>(xb, wqkvb, fc, qw, kw, qrope, krope, vtb);

  attn9<<<512, 256, 0, stream>>>(qrope, krope, vtb, ao);

  gemm_bt3<1><<<512, 256, 0, stream>>>(ao, wob, (void*)out, 4096, 2048, 2048, 16);
}

// Round 20
// 193.333 us; speedup vs baseline: 1.0320x; 1.0320x over previous
//
#include <hip/hip_runtime.h>

#define B_ 2
#define S_ 2048
#define D_ 2048
#define NH 16
#define NKV 8
#define HD 128
#define SCALE 0.08838834764831845f
#define CEXP 0.1275255f          // SCALE * log2(e)
#define RTHR 62.733f             // 8 / CEXP  (defer-max threshold, p <= 2^8)

typedef unsigned short u16;
typedef __attribute__((ext_vector_type(8))) short short8;
typedef __attribute__((ext_vector_type(4))) float f32x4;
typedef __attribute__((ext_vector_type(16))) float f32x16;
typedef __attribute__((ext_vector_type(4))) int i32x4;
typedef __attribute__((ext_vector_type(2))) int i32x2;

#define ASM_VMCNT(N) asm volatile("s_waitcnt vmcnt(" #N ")" ::: "memory")
#define MEMFENCE asm volatile("" ::: "memory")

__device__ __forceinline__ u16 f2b(float f) {
  union { float f; unsigned u; } c; c.f = f;
  unsigned u = c.u;
  return (u16)((u + 0x7fffu + ((u >> 16) & 1u)) >> 16);
}
__device__ __forceinline__ float b2f(u16 h) {
  union { unsigned u; float f; } c; c.u = ((unsigned)h) << 16;
  return c.f;
}
__device__ __forceinline__ float exp2f_fast(float x) {
  float r; asm("v_exp_f32 %0, %1" : "=v"(r) : "v"(x)); return r;
}
__device__ __forceinline__ int cvtpk(float a, float b) {  // low16=bf16(a), high16=bf16(b)
  int r; asm("v_cvt_pk_bf16_f32 %0, %1, %2" : "=v"(r) : "v"(a), "v"(b)); return r;
}
// swap: a.hi32lanes <-> b.lo32lanes (both regs updated)
__device__ __forceinline__ void pl32swap(int& a, int& b) {
  asm volatile("v_permlane32_swap_b32 %0, %1" : "+v"(a), "+v"(b));
}

__device__ __forceinline__ void load_lds16(const u16* g, u16* l) {
  __builtin_amdgcn_global_load_lds(
      (const __attribute__((address_space(1))) unsigned int*)g,
      (__attribute__((address_space(3))) unsigned int*)l, 16, 0, 0);
}

// ---------------- fused f32 -> bf16 conversion (all 5 tensors, 1 launch) ----------------
__global__ __launch_bounds__(256) void cvt_all(const float* __restrict__ x,
                                               const float* __restrict__ wq,
                                               const float* __restrict__ wk,
                                               const float* __restrict__ wv,
                                               const float* __restrict__ wo,
                                               u16* __restrict__ xb,
                                               u16* __restrict__ wqkvb,
                                               u16* __restrict__ wob) {
  const int blk = blockIdx.x;
  const float* src; u16* dst; int base;
  if (blk < 8192)       { src = x;  dst = xb;                  base = blk; }
  else if (blk < 12288) { src = wq; dst = wqkvb;               base = blk - 8192; }
  else if (blk < 14336) { src = wk; dst = wqkvb + 2048 * 2048; base = blk - 12288; }
  else if (blk < 16384) { src = wv; dst = wqkvb + 3072 * 2048; base = blk - 14336; }
  else                  { src = wo; dst = wob;                 base = blk - 16384; }
  int i = base * 256 + threadIdx.x;
  float4 v = ((const float4*)src)[i];
  u16 o0 = f2b(v.x), o1 = f2b(v.y), o2 = f2b(v.z), o3 = f2b(v.w);
  unsigned long long packed = (unsigned long long)o0 | ((unsigned long long)o1 << 16) |
                              ((unsigned long long)o2 << 32) | ((unsigned long long)o3 << 48);
  ((unsigned long long*)dst)[i] = packed;
}

// ---------------- QKV GEMM + fused RMSNorm/RoPE/V-transpose epilogue ----------------
// 256x128 tile, 8 waves, single-buffer LDS via global_load_lds (R16/R18 known-good:
// 82.3 us, FETCH 74.8 MB). 128^2 variant (R19) raised FETCH to 129.6 MB -> reverted.
#define LDA4Q(dst, SRC) \
  { _Pragma("unroll") for (int i2 = 0; i2 < 4; ++i2) { \
      const int arow = wr * 64 + i2 * 16 + r; \
      dst[i2] = *(const short8*)&(SRC)[arow * 32 + ((hi ^ ((arow >> 1) & 3)) << 3)]; } }
#define LDB4Q(dst, SRC) \
  { _Pragma("unroll") for (int n2 = 0; n2 < 4; ++n2) { \
      const int brow = wc * 64 + n2 * 16 + r; \
      dst[n2] = *(const short8*)&(SRC)[brow * 32 + ((hi ^ ((brow >> 1) & 3)) << 3)]; } }
#define MFMA16Q(AF, BF) \
  { __builtin_amdgcn_s_setprio(1); \
    _Pragma("unroll") for (int i2 = 0; i2 < 4; ++i2) \
    _Pragma("unroll") for (int n2 = 0; n2 < 4; ++n2) \
      acc[i2][n2] = __builtin_amdgcn_mfma_f32_16x16x32_bf16(AF[i2], BF[n2], acc[i2][n2], 0, 0, 0); \
    __builtin_amdgcn_s_setprio(0); }

__global__ __launch_bounds__(512, 4) void gemm_qkv_fused(const u16* __restrict__ A,
                                                         const u16* __restrict__ Bm,
                                                         const float* __restrict__ fc,
                                                         const float* __restrict__ qw,
                                                         const float* __restrict__ kw,
                                                         u16* __restrict__ qrope,
                                                         u16* __restrict__ krope,
                                                         u16* __restrict__ vt) {
  __shared__ __align__(16) u16 As2[2][8192];   // [kc][256 rows x 32 k]  32 KB
  __shared__ __align__(16) u16 Bs2[2][4096];   // [kc][128 rows x 32 k]  16 KB
  __shared__ float sq[2][256];                 // cross-wave sumsq exchange  2 KB
  const int tid = threadIdx.x;
  const int wave = tid >> 6, lane = tid & 63;
  const int L = (blockIdx.x & 7) * 64 + (blockIdx.x >> 3);  // bijective XCD chunking
  const int bm = L >> 5, bn = L & 31;          // 16 x 32 tile grid
  const int wr = wave >> 1, wc = wave & 1;     // 4M x 2N waves; per-wave 64x64
  const int r = lane & 15, hi = lane >> 4;
  const int rowA0 = bm * 256, rowB0 = bn * 128;

  f32x4 acc[4][4];
#pragma unroll
  for (int mi = 0; mi < 4; ++mi)
#pragma unroll
    for (int ni = 0; ni < 4; ++ni) acc[mi][ni] = (f32x4){0.f, 0.f, 0.f, 0.f};

  auto stage_ha = [&](u16* lds, int kcol) {
#pragma unroll
    for (int l = 0; l < 2; ++l) {
      const int p = wave * 2048 + l * 1024 + lane * 16;
      const int row = p >> 6, slot = (p >> 4) & 3;
      const int kg = slot ^ ((row >> 1) & 3);
      load_lds16(A + (size_t)(rowA0 + row) * 2048 + kcol + kg * 8,
                 lds + ((wave * 2048 + l * 1024) >> 1));
    }
  };
  auto stage_hb = [&](u16* lds, int kcol) {
    const int p = wave * 1024 + lane * 16;
    const int row = p >> 6, slot = (p >> 4) & 3;
    const int kg = slot ^ ((row >> 1) & 3);
    load_lds16(Bm + (size_t)(rowB0 + row) * 2048 + kcol + kg * 8,
               lds + ((wave * 1024) >> 1));
  };

  for (int kt = 0; kt < 32; ++kt) {
    const int k0 = kt << 6;
    stage_ha(As2[0], k0);
    stage_hb(Bs2[0], k0);
    stage_ha(As2[1], k0 + 32);
    stage_hb(Bs2[1], k0 + 32);
    ASM_VMCNT(0);
    __builtin_amdgcn_s_barrier();
    MEMFENCE;
    short8 af[4], bf[4];
    LDB4Q(bf, Bs2[0]); LDA4Q(af, As2[0]);
    MFMA16Q(af, bf);
    LDB4Q(bf, Bs2[1]); LDA4Q(af, As2[1]);
    MFMA16Q(af, bf);
    MEMFENCE;
    __builtin_amdgcn_s_barrier();   // all reads done before next stage overwrites
  }

  // ---- fused epilogue ----
  if (bn >= 24) {
    // V head: no norm/rope; store transposed vt[(b*8+hv)*128+d][s]
    const int hv = bn - 24;
#pragma unroll
    for (int mi = 0; mi < 4; ++mi) {
      const int tok0 = bm * 256 + wr * 64 + mi * 16 + hi * 4;
      const int bb = tok0 >> 11, sl = tok0 & 2047;
#pragma unroll
      for (int ni = 0; ni < 4; ++ni) {
        const int d = wc * 64 + ni * 16 + r;
        int w0 = cvtpk(acc[mi][ni][0], acc[mi][ni][1]);
        int w1 = cvtpk(acc[mi][ni][2], acc[mi][ni][3]);
        i32x2 pk = (i32x2){w0, w1};
        *(i32x2*)(vt + ((size_t)(bb * 8 + hv) * 128 + d) * 2048 + sl) = pk;
      }
    }
  } else {
    // Q/K head: RMSNorm over the 128-col row, then RoPE, then store.
    const float* nw = (bn < 16) ? qw : kw;
    float nwv[4];
#pragma unroll
    for (int ni = 0; ni < 4; ++ni) nwv[ni] = nw[wc * 64 + ni * 16 + r];
    float ssq[4][4];
#pragma unroll
    for (int mi = 0; mi < 4; ++mi)
#pragma unroll
      for (int r2 = 0; r2 < 4; ++r2) {
        float s4 = 0.f;
#pragma unroll
        for (int ni = 0; ni < 4; ++ni) {
          float a = acc[mi][ni][r2];
          s4 = __builtin_fmaf(a, a, s4);
        }
#pragma unroll
        for (int mk = 1; mk < 16; mk <<= 1) s4 += __shfl_xor(s4, mk, 64);
        ssq[mi][r2] = s4;
      }
    if (r == 0) {
#pragma unroll
      for (int mi = 0; mi < 4; ++mi)
#pragma unroll
        for (int r2 = 0; r2 < 4; ++r2)
          sq[wc][wr * 64 + mi * 16 + hi * 4 + r2] = ssq[mi][r2];
    }
    __syncthreads();   // block-uniform branch (bn uniform) -> safe
    u16* outp = (bn < 16) ? qrope : krope;
#pragma unroll
    for (int mi = 0; mi < 4; ++mi) {
      const int tok0 = bm * 256 + wr * 64 + mi * 16 + hi * 4;
      const int bb = tok0 >> 11;
      const size_t headbase = (bn < 16) ? ((size_t)(bb * 16 + bn) * 2048)
                                        : ((size_t)(bb * 8 + (bn - 16)) * 2048);
#pragma unroll
      for (int r2 = 0; r2 < 4; ++r2) {
        const int sl = (tok0 + r2) & 2047;
        const float tot = ssq[mi][r2] + sq[wc ^ 1][wr * 64 + mi * 16 + hi * 4 + r2];
        const float rms = rsqrtf(tot * (1.0f / 128.0f) + 1e-6f);
#pragma unroll
        for (int ni = 0; ni < 4; ++ni) {
          const int d = wc * 64 + ni * 16 + r;
          float val = acc[mi][ni][r2] * rms * nwv[ni];
          float prt = __shfl_xor(val, 1, 64);
          const float2 cs = *(const float2*)&fc[(size_t)(sl * 64 + (d >> 1)) * 2];
          float outv = (r & 1) ? (prt * cs.y + val * cs.x)     // odd col: tr*sin + ti*cos
                               : (val * cs.x - prt * cs.y);    // even col: tr*cos - ti*sin
          outp[(headbase + sl) * 128 + d] = f2b(outv);
        }
      }
    }
  }
}

// ---------------- out-GEMM (128^2): single-buffer LDS, co-resident blocks ----------
template<int OUTF32>
__global__ __launch_bounds__(256, 4) void gemm_bt3(const u16* __restrict__ A, const u16* __restrict__ Bm,
                                                   void* __restrict__ Cv, int M, int N, int K, int nbn) {
  __shared__ __align__(16) u16 As[128 * 64];   // 16 KB
  __shared__ __align__(16) u16 Bs[128 * 64];   // 16 KB
  const int tid = threadIdx.x;
  const int wave = tid >> 6, lane = tid & 63;
  const int nwg = gridDim.x, cpx = nwg >> 3;
  const int L = (blockIdx.x & 7) * cpx + (blockIdx.x >> 3);
  const int bm = L / nbn, bn = L % nbn;
  const int wr = wave >> 1, wc = wave & 1;
  const int r = lane & 15, hi = lane >> 4;

  f32x4 acc[4][4];
#pragma unroll
  for (int m = 0; m < 4; ++m)
#pragma unroll
    for (int n = 0; n < 4; ++n) acc[m][n] = (f32x4){0.f, 0.f, 0.f, 0.f};

  const int gslot = (lane & 7) ^ (lane >> 3);
  const int srow = lane >> 3;

  auto stage = [&](int k0) {
#pragma unroll
    for (int jj = 0; jj < 4; ++jj) {
      int j = wave * 4 + jj;
      int row = j * 8 + srow;
      load_lds16(A + (size_t)(bm * 128 + row) * K + k0 + gslot * 8, &As[j * 512]);
      load_lds16(Bm + (size_t)(bn * 128 + row) * K + k0 + gslot * 8, &Bs[j * 512]);
    }
  };

  const int nk = K >> 6;
  for (int kt = 0; kt < nk; ++kt) {
    stage(kt << 6);
    ASM_VMCNT(0);
    __builtin_amdgcn_s_barrier();
    MEMFENCE;
#pragma unroll
    for (int kc = 0; kc < 2; ++kc) {
      short8 af[4], bfr[4];
#pragma unroll
      for (int m = 0; m < 4; ++m) {
        int row = wr * 64 + m * 16 + r;
        int slot = (hi + kc * 4) ^ (row & 7);
        af[m] = *(const short8*)&As[row * 64 + slot * 8];
      }
#pragma unroll
      for (int n = 0; n < 4; ++n) {
        int row = wc * 64 + n * 16 + r;
        int slot = (hi + kc * 4) ^ (row & 7);
        bfr[n] = *(const short8*)&Bs[row * 64 + slot * 8];
      }
#pragma unroll
      for (int m = 0; m < 4; ++m)
#pragma unroll
        for (int n = 0; n < 4; ++n)
          acc[m][n] = __builtin_amdgcn_mfma_f32_16x16x32_bf16(af[m], bfr[n], acc[m][n], 0, 0, 0);
    }
    MEMFENCE;
    __builtin_amdgcn_s_barrier();   // reads done before next stage overwrites
  }

#pragma unroll
  for (int m = 0; m < 4; ++m)
#pragma unroll
    for (int n = 0; n < 4; ++n)
#pragma unroll
      for (int r2 = 0; r2 < 4; ++r2) {
        int grow = bm * 128 + wr * 64 + m * 16 + hi * 4 + r2;
        int gcol = bn * 128 + wc * 64 + n * 16 + r;
        if (OUTF32)
          ((float*)Cv)[(size_t)grow * N + gcol] = acc[m][n][r2];
        else
          ((u16*)Cv)[(size_t)grow * N + gcol] = f2b(acc[m][n][r2]);
      }
}

// ---------------- causal flash attention v9: ONE barrier per step ----------------
__global__ __launch_bounds__(256, 2) void attn9(const u16* __restrict__ qr, const u16* __restrict__ kr,
                                                const u16* __restrict__ vt, u16* __restrict__ ao) {
  __shared__ __align__(16) u16 Ks[2][64 * 128];
  __shared__ __align__(16) u16 Vs[2][128 * 64];
  const int tid = threadIdx.x, wave = tid >> 6, lane = tid & 63;
  const int ql = lane & 31, lh = lane >> 5;

  const int blk = blockIdx.x;
  const int half = blk >> 8;                 // 0: big tiles, 1: complementary small tiles
  const int xcd = blk & 7;
  const int idx = (blk >> 3) & 31;
  const int bh = xcd * 4 + (idx & 3);
  const int pp = idx >> 2;                   // 0..7
  const int t = half ? pp : 15 - pp;
  const int b = bh >> 4, h = bh & 15, hkv = h >> 1;

  const u16* Q  = qr + (size_t)(b * 16 + h) * S_ * HD;
  const u16* Kg = kr + (size_t)(b * 8 + hkv) * S_ * HD;
  const u16* Vg = vt + (size_t)(b * 8 + hkv) * HD * S_;

  const int q0w = t * 128 + wave * 32;
  const int nsteps = 2 * (t + 1);

  short8 qf[8];
#pragma unroll
  for (int ki = 0; ki < 8; ++ki)
    qf[ki] = *(const short8*)(Q + (size_t)(q0w + ql) * HD + ki * 16 + lh * 8);

  f32x16 o[4];
#pragma unroll
  for (int dt = 0; dt < 4; ++dt) o[dt] = 0.f;
  float m = -1e30f, l = 0.f;

  auto stage = [&](int buf, int kv0) {
#pragma unroll
    for (int inst = 0; inst < 4; ++inst) {
      int pp2 = wave * 4096 + inst * 1024 + lane * 16;
      int row = pp2 >> 8;
      int colb = (pp2 & 255) ^ ((row & 7) << 4);
      load_lds16(Kg + (((size_t)(kv0 + row)) << 7) + (colb >> 1),
                 &Ks[buf][(wave * 4096 + inst * 1024) >> 1]);
    }
#pragma unroll
    for (int inst = 0; inst < 4; ++inst) {
      int pp2 = wave * 4096 + inst * 1024 + lane * 16;
      int d = pp2 >> 7;
      int colb = (pp2 & 127) ^ ((d & 7) << 4);
      load_lds16(Vg + (size_t)d * S_ + kv0 + (colb >> 1),
                 &Vs[buf][(wave * 4096 + inst * 1024) >> 1]);
    }
  };

  stage(0, 0);
  for (int i = 0; i < nsteps; ++i) {
    const int kv0 = i * 64;
    const u16* kb = Ks[i & 1];
    const u16* vb = Vs[i & 1];

    ASM_VMCNT(0);                            // my stage(i) loads (issued last iter) done
    __builtin_amdgcn_s_barrier();            // everyone's drained; prev compute reads done
    MEMFENCE;                                // compute reads can't hoist above barrier
    if (i + 1 < nsteps) stage((i + 1) & 1, kv0 + 64);   // prefetch hides under compute(i)

    if (kv0 < q0w + 32) {
      f32x16 sacc[2];
      sacc[0] = 0.f; sacc[1] = 0.f;
      __builtin_amdgcn_s_setprio(1);
#pragma unroll
      for (int ki = 0; ki < 8; ++ki) {
        const int off = ki * 32 + lh * 16;
#pragma unroll
        for (int kvt = 0; kvt < 2; ++kvt) {
          const int row = kvt * 32 + ql;
          short8 kf = *(const short8*)&kb[(row << 7) + ((off ^ ((row & 7) << 4)) >> 1)];
          sacc[kvt] = __builtin_amdgcn_mfma_f32_32x32x16_bf16(kf, qf[ki], sacc[kvt], 0, 0, 0);
        }
      }
      __builtin_amdgcn_s_setprio(0);
      const int q = q0w + ql;
      if (kv0 + 64 > q0w) {
#pragma unroll
        for (int kvt = 0; kvt < 2; ++kvt) {
          const int kvb = kv0 + kvt * 32 + 4 * lh;
#pragma unroll
          for (int reg = 0; reg < 16; ++reg) {
            const int kvr = kvb + (reg & 3) + 8 * (reg >> 2);
            sacc[kvt][reg] = (kvr > q) ? -1e30f : sacc[kvt][reg];
          }
        }
      }
      float mx = sacc[0][0];
#pragma unroll
      for (int kvt = 0; kvt < 2; ++kvt)
#pragma unroll
        for (int reg = 0; reg < 16; ++reg) mx = fmaxf(mx, sacc[kvt][reg]);
      mx = fmaxf(mx, __shfl_xor(mx, 32, 64));
      if (__any(mx > m + RTHR)) {
        float mn = fmaxf(m, mx);
        float sc = exp2f_fast((m - mn) * CEXP);
        l *= sc;
        m = mn;
#pragma unroll
        for (int dt = 0; dt < 4; ++dt)
#pragma unroll
          for (int reg = 0; reg < 16; ++reg) o[dt][reg] *= sc;
      }
      short8 pf[4];
      const float mc = m * CEXP;
      float ps = 0.f;
#pragma unroll
      for (int kvt = 0; kvt < 2; ++kvt) {
        float pv[16];
#pragma unroll
        for (int reg = 0; reg < 16; ++reg) {
          pv[reg] = exp2f_fast(__builtin_fmaf(sacc[kvt][reg], CEXP, -mc));
          ps += pv[reg];
        }
        int A0 = cvtpk(pv[0], pv[1]),  B0 = cvtpk(pv[2], pv[3]);
        int C0 = cvtpk(pv[4], pv[5]),  D0 = cvtpk(pv[6], pv[7]);
        int A1 = cvtpk(pv[8], pv[9]),  B1 = cvtpk(pv[10], pv[11]);
        int C1 = cvtpk(pv[12], pv[13]), D1 = cvtpk(pv[14], pv[15]);
        pl32swap(A0, C0);
        pl32swap(B0, D0);
        pl32swap(A1, C1);
        pl32swap(B1, D1);
        i32x4 w0 = (i32x4){A0, B0, C0, D0};
        i32x4 w1 = (i32x4){A1, B1, C1, D1};
        pf[kvt * 2]     = *(short8*)&w0;
        pf[kvt * 2 + 1] = *(short8*)&w1;
      }
      l += ps;
      __builtin_amdgcn_s_setprio(1);
#pragma unroll
      for (int kc = 0; kc < 4; ++kc) {
        const int off = kc * 32 + lh * 16;
#pragma unroll
        for (int dt = 0; dt < 4; ++dt) {
          const int d = dt * 32 + ql;
          short8 vf = *(const short8*)&vb[(d << 6) + ((off ^ ((d & 7) << 4)) >> 1)];
          o[dt] = __builtin_amdgcn_mfma_f32_32x32x16_bf16(vf, pf[kc], o[dt], 0, 0, 0);
        }
      }
      __builtin_amdgcn_s_setprio(0);
    }
    MEMFENCE;                                // compute reads can't sink below next barrier
  }

  l += __shfl_xor(l, 32, 64);
  const float inv = 1.0f / l;
  const size_t rowoff = ((size_t)(b * 2048 + q0w + ql)) * 2048 + h * 128;
#pragma unroll
  for (int dt = 0; dt < 4; ++dt)
#pragma unroll
    for (int g = 0; g < 4; ++g) {
      const int d0 = dt * 32 + 8 * g + 4 * lh;
      int w0 = cvtpk(o[dt][4 * g] * inv, o[dt][4 * g + 1] * inv);
      int w1 = cvtpk(o[dt][4 * g + 2] * inv, o[dt][4 * g + 3] * inv);
      i32x2 pk = (i32x2){w0, w1};
      *(i32x2*)((u16*)ao + rowoff + d0) = pk;
    }
}

extern "C" void kernel_launch(void* const* d_in, const int* in_sizes, int n_in,
                              void* d_out, int out_size, void* d_ws, size_t ws_size,
                              hipStream_t stream) {
  const float* x = (const float*)d_in[0];
  const float* fc = (const float*)d_in[1];
  const float* wq = (const float*)d_in[2];
  const float* wk = (const float*)d_in[3];
  const float* wv = (const float*)d_in[4];
  const float* wo = (const float*)d_in[5];
  const float* qw = (const float*)d_in[6];
  const float* kw = (const float*)d_in[7];
  float* out = (float*)d_out;
  char* ws = (char*)d_ws;

  u16* xb    = (u16*)(ws);                 // [4096][2048] bf16   16 MB
  u16* wqkvb = (u16*)(ws + 16777216);      // [4096][2048] bf16   16 MB
  u16* wob   = (u16*)(ws + 33554432);      // [2048][2048] bf16    8 MB
  u16* qrope = (u16*)(ws + 75497472);      // [2][16][2048][128]  16 MB
  u16* krope = (u16*)(ws + 92274688);      // [2][8][2048][128]    8 MB
  u16* vtb   = (u16*)(ws + 100663296);     // [2][8][128][2048]    8 MB
  u16* ao    = (u16*)(ws + 109051904);     // [4096][2048] bf16   16 MB

  cvt_all<<<20480, 256, 0, stream>>>(x, wq, wk, wv, wo, xb, wqkvb, wob);

  gemm_qkv_fused<<<512, 512, 0, stream>>>(xb, wqkvb, fc, qw, kw, qrope, krope, vtb);

  attn9<<<512, 256, 0, stream>>>(qrope, krope, vtb, ao);

  gemm_bt3<1><<<512, 256, 0, stream>>>(ao, wob, (void*)out, 4096, 2048, 2048, 16);
}